// Round 8
// baseline (169.058 us; speedup 1.0000x reference)
//
#include <hip/hip_runtime.h>
#include <math.h>

#define H_IMG 1080
#define W_IMG 1920
#define NPIX (H_IMG * W_IMG)
#define W4 480                                 // W_IMG / 4
#define QUADS (NPIX / 4)                       // 518400
#define RB 2025                                // QUADS / 256, exact
#define NACC 27

// ---- workspace layout (byte offsets) ----
#define OFF_POSE     0                         // 16 f32
#define OFF_MINMAX   64                        // 2 u32
#define OFF_COUNT    128                       // 1 u32 ticket
#define OFF_SUMS     192                       // NACC f64 = 216 B
#define OFF_PARTIALS 512                       // NACC * RB f32 = 218700 B
#define OFF_ND16     219648                    // NPIX f16x4 (nx,ny,nz,d) = 16.6 MB
#define OFF_NDP      16808448                  // NPIX f16x8 row-pair table = 33.2 MB (+slack)

typedef _Float16 h4 __attribute__((ext_vector_type(4)));
typedef _Float16 h8 __attribute__((ext_vector_type(8)));

__device__ __forceinline__ float clampf(float x, float lo, float hi) {
    return fminf(fmaxf(x, lo), hi);
}

__global__ void k_init(const float* __restrict__ pose_in, float* __restrict__ ws_pose,
                       unsigned int* __restrict__ minmax, unsigned int* __restrict__ counter) {
    int t = threadIdx.x;
    if (t < 16) ws_pose[t] = pose_in[t];
    if (t == 16) { minmax[0] = 0x7F800000u; minmax[1] = 0u; }
    if (t == 17) *counter = 0u;
}

__global__ void k_minmax(const float4* __restrict__ dq, unsigned int* __restrict__ minmax) {
    int tid = blockIdx.x * blockDim.x + threadIdx.x;
    int stride = gridDim.x * blockDim.x;
    float mn = INFINITY, mx = -INFINITY;
    for (int i = tid; i < QUADS; i += stride) {
        float4 v = dq[i];
        mn = fminf(mn, fminf(fminf(v.x, v.y), fminf(v.z, v.w)));
        mx = fmaxf(mx, fmaxf(fmaxf(v.x, v.y), fmaxf(v.z, v.w)));
    }
    for (int off = 32; off > 0; off >>= 1) {
        mn = fminf(mn, __shfl_down(mn, off));
        mx = fmaxf(mx, __shfl_down(mx, off));
    }
    __shared__ float smn[4], smx[4];
    int lane = threadIdx.x & 63, wid = threadIdx.x >> 6;
    if (lane == 0) { smn[wid] = mn; smx[wid] = mx; }
    __syncthreads();
    if (threadIdx.x == 0) {
        for (int w = 1; w < 4; w++) { mn = fminf(mn, smn[w]); mx = fmaxf(mx, smx[w]); }
        atomicMin(&minmax[0], __float_as_uint(mn));  // positive floats: bit order == value order
        atomicMax(&minmax[1], __float_as_uint(mx));
    }
}

// masked normals + depth packed to f16x4 (8 B/px). 4 consecutive pixels per thread.
__global__ __launch_bounds__(256)
void k_nm(const float* __restrict__ depth1, const float* __restrict__ Kmat,
          const unsigned int* __restrict__ minmax, h4* __restrict__ nd16) {
    int tid = threadIdx.x;
    int qid = blockIdx.x * 256 + tid;          // grid exactly RB*256 == QUADS
    float fx = Kmat[0], cx = Kmat[2], fy = Kmat[4], cy = Kmat[5];
    float ifx = 1.f / fx, ify = 1.f / fy;
    float dmin = __uint_as_float(minmax[0]), dmax = __uint_as_float(minmax[1]);
    int j = qid / W4;
    int i0 = (qid - j * W4) * 4;
    int r0 = j > 0 ? j - 1 : 0;
    int r2 = j < H_IMG - 1 ? j + 1 : H_IMG - 1;
    int il = i0 > 0 ? i0 - 1 : 0;
    int ir = i0 + 4 < W_IMG ? i0 + 4 : W_IMG - 1;
    const float* rp[3] = { depth1 + (size_t)r0 * W_IMG,
                           depth1 + (size_t)j  * W_IMG,
                           depth1 + (size_t)r2 * W_IMG };
    float d[3][6];
#pragma unroll
    for (int r = 0; r < 3; r++) {
        float4 m = *reinterpret_cast<const float4*>(rp[r] + i0);
        d[r][0] = rp[r][il]; d[r][1] = m.x; d[r][2] = m.y; d[r][3] = m.z; d[r][4] = m.w; d[r][5] = rp[r][ir];
    }
    float rowc[3] = { ((float)r0 - cy) * ify, ((float)j - cy) * ify, ((float)r2 - cy) * ify };
    float colc[6];
#pragma unroll
    for (int c = 0; c < 6; c++) {
        int col = i0 - 1 + c; col = col < 0 ? 0 : (col > W_IMG - 1 ? W_IMG - 1 : col);
        colc[c] = ((float)col - cx) * ifx;
    }
    float vx[3][6], vy[3][6];
#pragma unroll
    for (int r = 0; r < 3; r++)
#pragma unroll
        for (int c = 0; c < 6; c++) { vx[r][c] = colc[c] * d[r][c]; vy[r][c] = rowc[r] * d[r][c]; }
    h4 out[4];
#pragma unroll
    for (int p = 0; p < 4; p++) {
        int a = p, b = p + 1, e = p + 2;
        float dxx = -vx[0][a] + vx[0][e] - 2.f * vx[1][a] + 2.f * vx[1][e] - vx[2][a] + vx[2][e];
        float dxy = -vy[0][a] + vy[0][e] - 2.f * vy[1][a] + 2.f * vy[1][e] - vy[2][a] + vy[2][e];
        float dxz = -d[0][a] + d[0][e] - 2.f * d[1][a] + 2.f * d[1][e] - d[2][a] + d[2][e];
        float dyx = -vx[0][a] - 2.f * vx[0][b] - vx[0][e] + vx[2][a] + 2.f * vx[2][b] + vx[2][e];
        float dyy = -vy[0][a] - 2.f * vy[0][b] - vy[0][e] + vy[2][a] + 2.f * vy[2][b] + vy[2][e];
        float dyz = -d[0][a] - 2.f * d[0][b] - d[0][e] + d[2][a] + 2.f * d[2][b] + d[2][e];
        float nx = dxy * dyz - dxz * dyy;
        float ny = dxz * dyx - dxx * dyz;
        float nz = dxx * dyy - dxy * dyx;
        float inv = 1.f / (sqrtf(nx * nx + ny * ny + nz * nz) + 1e-8f);
        float dc = d[1][b];
        bool invalid = (dc <= dmin) || (dc >= dmax);   // exact f32 compare pre-pack
        float s = invalid ? 0.f : inv;
        out[p][0] = (_Float16)(nx * s);
        out[p][1] = (_Float16)(ny * s);
        out[p][2] = (_Float16)(nz * s);
        out[p][3] = (_Float16)dc;
    }
    h4* dst = nd16 + (size_t)j * W_IMG + i0;
#pragma unroll
    for (int p = 0; p < 4; p++) dst[p] = out[p];
}

// row-pair table: ndp[j*W+i] = {nd16[j][i], nd16[min(j+1,H-1)][i]} (16 B).
// A pixel's 2x2 bilinear footprint = 2 adjacent 16 B chunks = ~1 cache line.
__global__ __launch_bounds__(256)
void k_pair(const uint2* __restrict__ nd16, uint4* __restrict__ ndp) {
    int qid = blockIdx.x * 256 + threadIdx.x;  // grid exactly RB*256 == QUADS
    int idx4 = qid * 4;
    int j = idx4 / W_IMG;                      // W%4==0: all 4 px in same row
    int j1 = j < H_IMG - 1 ? j + 1 : H_IMG - 1;
    int col = idx4 - j * W_IMG;
    const uint2* top = nd16 + (size_t)j * W_IMG + col;
    const uint2* bot = nd16 + (size_t)j1 * W_IMG + col;
    uint2 t[4], b[4];
#pragma unroll
    for (int p = 0; p < 4; p++) { t[p] = top[p]; b[p] = bot[p]; }
    uint4* dst = ndp + idx4;
#pragma unroll
    for (int p = 0; p < 4; p++) {
        uint4 o; o.x = t[p].x; o.y = t[p].y; o.z = b[p].x; o.w = b[p].y;
        dst[p] = o;
    }
}

// residual + Jacobian. Per pixel: 2 adjacent 16 B gathers fetch all 4 corners.
__global__ __launch_bounds__(256)
void k_resid(const float* __restrict__ depth0, const float* __restrict__ Kmat,
             const h8* __restrict__ ndp, const float* __restrict__ pose,
             float* __restrict__ partials) {
    float fx = Kmat[0], cx = Kmat[2], fy = Kmat[4], cy = Kmat[5];
    float ifx = 1.f / fx, ify = 1.f / fy;
    float R00 = pose[0], R01 = pose[1], R02 = pose[2],  t0 = pose[3];
    float R10 = pose[4], R11 = pose[5], R12 = pose[6],  t1 = pose[7];
    float R20 = pose[8], R21 = pose[9], R22 = pose[10], t2 = pose[11];

    float acc[NACC];
#pragma unroll
    for (int k = 0; k < NACC; k++) acc[k] = 0.f;

    int tid = threadIdx.x;
    int base = blockIdx.x * 1024;              // grid*1024 == NPIX exactly

    float d0s[4];
#pragma unroll
    for (int p = 0; p < 4; p++) d0s[p] = depth0[base + p * 256 + tid];  // coalesced

    float px[4], py[4], pz[4], wx[4], wy[4];
    int x0[4], y0[4], y1v[4];
    bool inview[4];
#pragma unroll
    for (int p = 0; p < 4; p++) {
        int idx = base + p * 256 + tid;
        int j = idx / W_IMG;
        int i = idx - j * W_IMG;
        float d0 = d0s[p];
        float v0x = ((float)i - cx) * ifx * d0;
        float v0y = ((float)j - cy) * ify * d0;
        float X = R00 * v0x + R01 * v0y + R02 * d0 + t0;
        float Y = R10 * v0x + R11 * v0y + R12 * d0 + t1;
        float Z = R20 * v0x + R21 * v0y + R22 * d0 + t2;
        float u, v; bool iv;
        if (Z > 1e-6f) {
            float rz = 1.f / Z;
            u = X * rz * fx + cx;
            v = Y * rz * fy + cy;
            iv = (u > 0.f) && (u < (float)(W_IMG - 1)) && (v > 0.f) && (v < (float)(H_IMG - 1));
        } else { u = 0.f; v = 0.f; iv = false; }
        float uc = clampf(u, 0.f, (float)(W_IMG - 1));
        float vc = clampf(v, 0.f, (float)(H_IMG - 1));
        float x0f = floorf(uc), y0f = floorf(vc);
        x0[p] = (int)x0f; y0[p] = (int)y0f;
        y1v[p] = min(y0[p] + 1, H_IMG - 1);
        wx[p] = uc - x0f; wy[p] = vc - y0f;
        px[p] = X; py[p] = Y; pz[p] = Z; inview[p] = iv;
    }
    // 8 gathers of 16 B, all independent. A = {(y0,x0),(y1,x0)}, B = {(y0,x1),(y1,x1)}.
    h8 A[4], B[4];
#pragma unroll
    for (int p = 0; p < 4; p++) {
        int b0 = y0[p] * W_IMG + x0[p];
        A[p] = ndp[b0]; B[p] = ndp[b0 + 1];
    }
#pragma unroll
    for (int p = 0; p < 4; p++) {
        float w1x = 1.f - wx[p], w1y = 1.f - wy[p];
        float d00 = (float)A[p][3], d10 = (float)A[p][7];
        float d01 = (float)B[p][3], d11 = (float)B[p][7];
        float cX0 = ((float)x0[p] - cx) * ifx, cX1 = ((float)(x0[p] + 1) - cx) * ifx;
        float cY0 = ((float)y0[p] - cy) * ify, cY1 = ((float)y1v[p] - cy) * ify;
        float rvx = (cX0 * d00 * w1x + cX1 * d01 * wx[p]) * w1y + (cX0 * d10 * w1x + cX1 * d11 * wx[p]) * wy[p];
        float rvy = (cY0 * d00 * w1x + cY0 * d01 * wx[p]) * w1y + (cY1 * d10 * w1x + cY1 * d11 * wx[p]) * wy[p];
        float rvz = (d00 * w1x + d01 * wx[p]) * w1y + (d10 * w1x + d11 * wx[p]) * wy[p];
        float rnx = ((float)A[p][0] * w1x + (float)B[p][0] * wx[p]) * w1y
                  + ((float)A[p][4] * w1x + (float)B[p][4] * wx[p]) * wy[p];
        float rny = ((float)A[p][1] * w1x + (float)B[p][1] * wx[p]) * w1y
                  + ((float)A[p][5] * w1x + (float)B[p][5] * wx[p]) * wy[p];
        float rnz = ((float)A[p][2] * w1x + (float)B[p][2] * wx[p]) * w1y
                  + ((float)A[p][6] * w1x + (float)B[p][6] * wx[p]) * wy[p];
        bool mask1 = rvz > 0.f;
        float ddx = px[p] - rvx, ddy = py[p] - rvy, ddz = pz[p] - rvz;
        bool occ = (!inview[p]) || (sqrtf(ddx * ddx + ddy * ddy + ddz * ddz) > 0.1f);
        bool bad = occ || !(d0s[p] > 0.f) || (!mask1);
        if (!bad) {
            float res = rnx * ddx + rny * ddy + rnz * ddz;
            float jv[6];
            jv[0] = -(py[p] * rnz - pz[p] * rny);
            jv[1] = -(pz[p] * rnx - px[p] * rnz);
            jv[2] = -(px[p] * rny - py[p] * rnx);
            jv[3] = -rnx; jv[4] = -rny; jv[5] = -rnz;
            int k = 0;
#pragma unroll
            for (int a = 0; a < 6; a++)
#pragma unroll
                for (int b = a; b < 6; b++) { acc[k] += jv[a] * jv[b]; k++; }
#pragma unroll
            for (int a = 0; a < 6; a++) acc[21 + a] += jv[a] * res;
        }
    }

    // block reduction: 2x shfl_xor pre-reduce (4 lanes) -> LDS [27][64] -> [27][8] -> f32 partial
    __shared__ float red[NACC][64];
    __shared__ float part2[NACC][8];
#pragma unroll
    for (int k = 0; k < NACC; k++) {
        float v = acc[k];
        v += __shfl_xor(v, 1);
        v += __shfl_xor(v, 2);
        if ((tid & 3) == 0) red[k][tid >> 2] = v;
    }
    __syncthreads();
    if (tid < NACC * 8) {
        int k = tid >> 3, seg = tid & 7;
        const float4* row = reinterpret_cast<const float4*>(&red[k][seg * 8]);
        float4 a = row[0], b = row[1];
        part2[k][seg] = (a.x + a.y + a.z + a.w) + (b.x + b.y + b.z + b.w);
    }
    __syncthreads();
    if (tid < NACC) {
        float s = 0.f;
#pragma unroll
        for (int m = 0; m < 8; m++) s += part2[tid][m];
        partials[(size_t)tid * RB + blockIdx.x] = s;
    }
}

// 27 blocks: block k reduces RB f32 partials (f64); last block runs the 6x6 GN solve.
__global__ __launch_bounds__(256)
void k_reduce_solve(const float* __restrict__ partials, double* __restrict__ sums,
                    unsigned int* __restrict__ counter, float* __restrict__ pose,
                    float* __restrict__ pose_out) {
    int k = blockIdx.x;
    int tid = threadIdx.x;
    double v = 0.0;
    for (int i = tid; i < RB; i += 256) v += (double)partials[(size_t)k * RB + i];
    for (int off = 32; off > 0; off >>= 1) v += __shfl_down(v, off);
    __shared__ double sw[4];
    __shared__ int amLast;
    int lane = tid & 63, wid = tid >> 6;
    if (lane == 0) sw[wid] = v;
    __syncthreads();
    if (tid == 0) {
        sums[k] = sw[0] + sw[1] + sw[2] + sw[3];
        __threadfence();
        unsigned int old = atomicAdd(counter, 1u);
        amLast = (old == NACC - 1) ? 1 : 0;
    }
    __syncthreads();
    if (!amLast) return;
    __threadfence();

    if (tid == 0) {
        double ssum[NACC];
        for (int q = 0; q < NACC; q++) ssum[q] = sums[q];
        double sM[6][7];
        int kk = 0;
        for (int a = 0; a < 6; a++)
            for (int c = a; c < 6; c++) {
                double s = ssum[kk++];
                sM[a][c] = s; sM[c][a] = s;
            }
        double tr = sM[0][0] + sM[1][1] + sM[2][2] + sM[3][3] + sM[4][4] + sM[5][5];
        for (int a = 0; a < 6; a++) sM[a][a] += tr * 0.001;
        for (int a = 0; a < 6; a++) sM[a][6] = ssum[21 + a];
        for (int c = 0; c < 6; c++) {
            int piv = c;
            double best = fabs(sM[c][c]);
            for (int r = c + 1; r < 6; r++) {
                double vv = fabs(sM[r][c]);
                if (vv > best) { best = vv; piv = r; }
            }
            if (piv != c)
                for (int q = c; q < 7; q++) { double t = sM[c][q]; sM[c][q] = sM[piv][q]; sM[piv][q] = t; }
            double pv = sM[c][c];
            for (int r = 0; r < 6; r++) {
                if (r == c) continue;
                double f = sM[r][c] / pv;
                for (int q = c; q < 7; q++) sM[r][q] -= f * sM[c][q];
            }
        }
        double xi0 = sM[0][6] / sM[0][0], xi1 = sM[1][6] / sM[1][1], xi2 = sM[2][6] / sM[2][2];
        double xi3 = sM[3][6] / sM[3][3], xi4 = sM[4][6] / sM[4][4], xi5 = sM[5][6] / sM[5][5];
        double th = sqrt(xi0 * xi0 + xi1 * xi1 + xi2 * xi2);
        double dR[3][3] = {{1, 0, 0}, {0, 1, 0}, {0, 0, 1}};
        if (th > 1e-10) {
            double sA = sin(th) / th;
            double sB = (1.0 - cos(th)) / (th * th);
            double wh[3][3] = {{0, -xi2, xi1}, {xi2, 0, -xi0}, {-xi1, xi0, 0}};
#pragma unroll
            for (int r = 0; r < 3; r++)
#pragma unroll
                for (int cc = 0; cc < 3; cc++) {
                    double w2 = 0;
#pragma unroll
                    for (int m = 0; m < 3; m++) w2 += wh[r][m] * wh[m][cc];
                    dR[r][cc] = (r == cc ? 1.0 : 0.0) + sA * wh[r][cc] + sB * w2;
                }
        }
        double R[3][3], t[3];
#pragma unroll
        for (int r = 0; r < 3; r++) {
#pragma unroll
            for (int cc = 0; cc < 3; cc++) R[r][cc] = pose[r * 4 + cc];
            t[r] = pose[r * 4 + 3];
        }
        double xt[3] = {xi3, xi4, xi5};
#pragma unroll
        for (int r = 0; r < 3; r++) {
#pragma unroll
            for (int cc = 0; cc < 3; cc++) {
                double s = 0;
#pragma unroll
                for (int m = 0; m < 3; m++) s += dR[r][m] * R[m][cc];
                pose[r * 4 + cc] = (float)s;
            }
            pose[r * 4 + 3] = (float)(dR[r][0] * t[0] + dR[r][1] * t[1] + dR[r][2] * t[2] + xt[r]);
        }
        *counter = 0u;                         // re-arm for next dispatch / replay
        for (int q = 0; q < 16; q++) pose_out[q] = pose[q];
    }
}

extern "C" void kernel_launch(void* const* d_in, const int* in_sizes, int n_in,
                              void* d_out, int out_size, void* d_ws, size_t ws_size,
                              hipStream_t stream) {
    const float* pose_in = (const float*)d_in[0];
    const float* depth0 = (const float*)d_in[1];
    const float* depth1 = (const float*)d_in[2];
    const float* K = (const float*)d_in[3];
    float* out = (float*)d_out;
    char* ws = (char*)d_ws;
    float* ws_pose = (float*)(ws + OFF_POSE);
    unsigned int* minmax = (unsigned int*)(ws + OFF_MINMAX);
    unsigned int* counter = (unsigned int*)(ws + OFF_COUNT);
    double* sums = (double*)(ws + OFF_SUMS);
    float* partials = (float*)(ws + OFF_PARTIALS);
    h4* nd16 = (h4*)(ws + OFF_ND16);
    void* ndp = (void*)(ws + OFF_NDP);

    k_init<<<1, 64, 0, stream>>>(pose_in, ws_pose, minmax, counter);
    k_minmax<<<1024, 256, 0, stream>>>((const float4*)depth1, minmax);
    k_nm<<<RB, 256, 0, stream>>>(depth1, K, minmax, nd16);
    k_pair<<<RB, 256, 0, stream>>>((const uint2*)nd16, (uint4*)ndp);
    for (int it = 0; it < 3; ++it) {
        k_resid<<<RB, 256, 0, stream>>>(depth0, K, (const h8*)ndp, ws_pose, partials);
        k_reduce_solve<<<NACC, 256, 0, stream>>>(partials, sums, counter, ws_pose, out);
    }
}

// Round 9
// 157.163 us; speedup vs baseline: 1.0757x; 1.0757x over previous
//
#include <hip/hip_runtime.h>
#include <math.h>

#define H_IMG 1080
#define W_IMG 1920
#define NPIX (H_IMG * W_IMG)
#define W4 480                                 // W_IMG / 4
#define QUADS (NPIX / 4)                       // 518400
#define RB 2025                                // QUADS / 256, exact
#define NACC 27

// ---- workspace layout (byte offsets) ----
#define OFF_POSE     0                         // 16 f32
#define OFF_MINMAX   64                        // 2 u32
#define OFF_COUNT    128                       // 1 u32 ticket
#define OFF_SUMS     192                       // NACC f64
#define OFF_PARTIALS 512                       // NACC * RB f32 = 218700 B
#define OFF_ND4      220160                    // NPIX u32 {u16 d, s8 ox, s8 oy} = 8.3 MB
#define OFF_NDP      8515584                   // NPIX uint2 row-pair = 16.6 MB

typedef uint4 uint4_a8 __attribute__((aligned(8)));

__device__ __forceinline__ float clampf(float x, float lo, float hi) {
    return fminf(fmaxf(x, lo), hi);
}

// decode 4B record -> depth + unit normal (zero if masked)
__device__ __forceinline__ void dec4(unsigned int w, float dmin, float scale,
                                     float& d, float& nx, float& ny, float& nz) {
    d = dmin + (float)(w & 0xffffu) * scale;
    unsigned int code = w >> 16;
    int ex = (int)(signed char)(code & 0xffu);
    int ey = (int)(signed char)(code >> 8);
    float px = (float)ex * (1.f / 127.f);
    float py = (float)ey * (1.f / 127.f);
    float z = 1.f - fabsf(px) - fabsf(py);
    float xo = (1.f - fabsf(py)) * (px >= 0.f ? 1.f : -1.f);
    float yo = (1.f - fabsf(px)) * (py >= 0.f ? 1.f : -1.f);
    float x = z < 0.f ? xo : px;
    float y = z < 0.f ? yo : py;
    float rn = rsqrtf(x * x + y * y + z * z + 1e-20f);
    float m = (code == 0x8080u) ? 0.f : rn;
    nx = x * m; ny = y * m; nz = z * m;
}

__global__ void k_init(const float* __restrict__ pose_in, float* __restrict__ ws_pose,
                       unsigned int* __restrict__ minmax, unsigned int* __restrict__ counter) {
    int t = threadIdx.x;
    if (t < 16) ws_pose[t] = pose_in[t];
    if (t == 16) { minmax[0] = 0x7F800000u; minmax[1] = 0u; }
    if (t == 17) *counter = 0u;
}

__global__ void k_minmax(const float4* __restrict__ dq, unsigned int* __restrict__ minmax) {
    int tid = blockIdx.x * blockDim.x + threadIdx.x;
    int stride = gridDim.x * blockDim.x;
    float mn = INFINITY, mx = -INFINITY;
    for (int i = tid; i < QUADS; i += stride) {
        float4 v = dq[i];
        mn = fminf(mn, fminf(fminf(v.x, v.y), fminf(v.z, v.w)));
        mx = fmaxf(mx, fmaxf(fmaxf(v.x, v.y), fmaxf(v.z, v.w)));
    }
    for (int off = 32; off > 0; off >>= 1) {
        mn = fminf(mn, __shfl_down(mn, off));
        mx = fmaxf(mx, __shfl_down(mx, off));
    }
    __shared__ float smn[4], smx[4];
    int lane = threadIdx.x & 63, wid = threadIdx.x >> 6;
    if (lane == 0) { smn[wid] = mn; smx[wid] = mx; }
    __syncthreads();
    if (threadIdx.x == 0) {
        for (int w = 1; w < 4; w++) { mn = fminf(mn, smn[w]); mx = fmaxf(mx, smx[w]); }
        atomicMin(&minmax[0], __float_as_uint(mn));  // positive floats: bit order == value order
        atomicMax(&minmax[1], __float_as_uint(mx));
    }
}

// masked normals (octa s8x2) + depth (u16 fixed over [dmin,dmax]) -> 4 B/px.
__global__ __launch_bounds__(256)
void k_nm(const float* __restrict__ depth1, const float* __restrict__ Kmat,
          const unsigned int* __restrict__ minmax, unsigned int* __restrict__ nd4) {
    int tid = threadIdx.x;
    int qid = blockIdx.x * 256 + tid;          // grid exactly RB*256 == QUADS
    float fx = Kmat[0], cx = Kmat[2], fy = Kmat[4], cy = Kmat[5];
    float ifx = 1.f / fx, ify = 1.f / fy;
    float dmin = __uint_as_float(minmax[0]), dmax = __uint_as_float(minmax[1]);
    float inv_scale = 65535.f / (dmax - dmin);
    int j = qid / W4;
    int i0 = (qid - j * W4) * 4;
    int r0 = j > 0 ? j - 1 : 0;
    int r2 = j < H_IMG - 1 ? j + 1 : H_IMG - 1;
    int il = i0 > 0 ? i0 - 1 : 0;
    int ir = i0 + 4 < W_IMG ? i0 + 4 : W_IMG - 1;
    const float* rp[3] = { depth1 + (size_t)r0 * W_IMG,
                           depth1 + (size_t)j  * W_IMG,
                           depth1 + (size_t)r2 * W_IMG };
    float d[3][6];
#pragma unroll
    for (int r = 0; r < 3; r++) {
        float4 m = *reinterpret_cast<const float4*>(rp[r] + i0);
        d[r][0] = rp[r][il]; d[r][1] = m.x; d[r][2] = m.y; d[r][3] = m.z; d[r][4] = m.w; d[r][5] = rp[r][ir];
    }
    float rowc[3] = { ((float)r0 - cy) * ify, ((float)j - cy) * ify, ((float)r2 - cy) * ify };
    float colc[6];
#pragma unroll
    for (int c = 0; c < 6; c++) {
        int col = i0 - 1 + c; col = col < 0 ? 0 : (col > W_IMG - 1 ? W_IMG - 1 : col);
        colc[c] = ((float)col - cx) * ifx;
    }
    float vx[3][6], vy[3][6];
#pragma unroll
    for (int r = 0; r < 3; r++)
#pragma unroll
        for (int c = 0; c < 6; c++) { vx[r][c] = colc[c] * d[r][c]; vy[r][c] = rowc[r] * d[r][c]; }
    unsigned int out[4];
#pragma unroll
    for (int p = 0; p < 4; p++) {
        int a = p, b = p + 1, e = p + 2;
        float dxx = -vx[0][a] + vx[0][e] - 2.f * vx[1][a] + 2.f * vx[1][e] - vx[2][a] + vx[2][e];
        float dxy = -vy[0][a] + vy[0][e] - 2.f * vy[1][a] + 2.f * vy[1][e] - vy[2][a] + vy[2][e];
        float dxz = -d[0][a] + d[0][e] - 2.f * d[1][a] + 2.f * d[1][e] - d[2][a] + d[2][e];
        float dyx = -vx[0][a] - 2.f * vx[0][b] - vx[0][e] + vx[2][a] + 2.f * vx[2][b] + vx[2][e];
        float dyy = -vy[0][a] - 2.f * vy[0][b] - vy[0][e] + vy[2][a] + 2.f * vy[2][b] + vy[2][e];
        float dyz = -d[0][a] - 2.f * d[0][b] - d[0][e] + d[2][a] + 2.f * d[2][b] + d[2][e];
        float nx = dxy * dyz - dxz * dyy;
        float ny = dxz * dyx - dxx * dyz;
        float nz = dxx * dyy - dxy * dyx;
        float inv = 1.f / (sqrtf(nx * nx + ny * ny + nz * nz) + 1e-8f);
        float dc = d[1][b];
        bool invalid = (dc <= dmin) || (dc >= dmax);   // exact f32 compare pre-pack
        float s = invalid ? 0.f : inv;
        nx *= s; ny *= s; nz *= s;
        // octahedral encode; zero normal -> reserved 0x8080
        float l1 = fabsf(nx) + fabsf(ny) + fabsf(nz);
        unsigned int code;
        if (l1 > 0.f) {
            float rl = 1.f / l1;
            float px = nx * rl, py = ny * rl;
            if (nz < 0.f) {
                float ox = (1.f - fabsf(py)) * (px >= 0.f ? 1.f : -1.f);
                float oy = (1.f - fabsf(px)) * (py >= 0.f ? 1.f : -1.f);
                px = ox; py = oy;
            }
            int ex = (int)rintf(px * 127.f);
            int ey = (int)rintf(py * 127.f);
            code = ((unsigned int)(ex & 0xff)) | (((unsigned int)(ey & 0xff)) << 8);
        } else code = 0x8080u;
        float dq = clampf(rintf((dc - dmin) * inv_scale), 0.f, 65535.f);
        out[p] = (unsigned int)dq | (code << 16);
    }
    *reinterpret_cast<uint4*>(nd4 + (size_t)j * W_IMG + i0) =
        make_uint4(out[0], out[1], out[2], out[3]);
}

// row-pair table: ndp[j*W+i] = {nd4[j][i], nd4[min(j+1,H-1)][i]} (8 B).
// One pixel's 2x2 footprint = ndp[x0], ndp[x0+1] = one 16 B gather.
__global__ __launch_bounds__(256)
void k_pair(const unsigned int* __restrict__ nd4, uint2* __restrict__ ndp) {
    int qid = blockIdx.x * 256 + threadIdx.x;  // grid exactly RB*256 == QUADS
    int idx4 = qid * 4;
    int j = idx4 / W_IMG;                      // W%4==0: all 4 px in same row
    int j1 = j < H_IMG - 1 ? j + 1 : H_IMG - 1;
    int col = idx4 - j * W_IMG;
    uint4 t = *reinterpret_cast<const uint4*>(nd4 + (size_t)j * W_IMG + col);
    uint4 b = *reinterpret_cast<const uint4*>(nd4 + (size_t)j1 * W_IMG + col);
    uint4* dst = reinterpret_cast<uint4*>(ndp + idx4);
    dst[0] = make_uint4(t.x, b.x, t.y, b.y);
    dst[1] = make_uint4(t.z, b.z, t.w, b.w);
}

// residual + Jacobian. ONE 16 B gather per in-view pixel fetches all 4 corners.
__global__ __launch_bounds__(256)
void k_resid(const float* __restrict__ depth0, const float* __restrict__ Kmat,
             const uint2* __restrict__ ndp, const unsigned int* __restrict__ minmax,
             const float* __restrict__ pose, float* __restrict__ partials) {
    float fx = Kmat[0], cx = Kmat[2], fy = Kmat[4], cy = Kmat[5];
    float ifx = 1.f / fx, ify = 1.f / fy;
    float R00 = pose[0], R01 = pose[1], R02 = pose[2],  t0 = pose[3];
    float R10 = pose[4], R11 = pose[5], R12 = pose[6],  t1 = pose[7];
    float R20 = pose[8], R21 = pose[9], R22 = pose[10], t2 = pose[11];
    float dmin = __uint_as_float(minmax[0]);
    float dmax = __uint_as_float(minmax[1]);
    float scale = (dmax - dmin) * (1.f / 65535.f);

    float acc[NACC];
#pragma unroll
    for (int k = 0; k < NACC; k++) acc[k] = 0.f;

    int tid = threadIdx.x;
    int base = blockIdx.x * 1024;              // grid*1024 == NPIX exactly

    float d0s[4];
#pragma unroll
    for (int p = 0; p < 4; p++) d0s[p] = depth0[base + p * 256 + tid];  // coalesced

    float px[4], py[4], pz[4], wx[4], wy[4];
    int x0[4], y0[4];
    bool inview[4];
#pragma unroll
    for (int p = 0; p < 4; p++) {
        int idx = base + p * 256 + tid;
        int j = idx / W_IMG;
        int i = idx - j * W_IMG;
        float d0 = d0s[p];
        float v0x = ((float)i - cx) * ifx * d0;
        float v0y = ((float)j - cy) * ify * d0;
        float X = R00 * v0x + R01 * v0y + R02 * d0 + t0;
        float Y = R10 * v0x + R11 * v0y + R12 * d0 + t1;
        float Z = R20 * v0x + R21 * v0y + R22 * d0 + t2;
        float u, v; bool iv;
        if (Z > 1e-6f) {
            float rz = 1.f / Z;
            u = X * rz * fx + cx;
            v = Y * rz * fy + cy;
            iv = (u > 0.f) && (u < (float)(W_IMG - 1)) && (v > 0.f) && (v < (float)(H_IMG - 1));
        } else { u = 0.f; v = 0.f; iv = false; }
        // for inview px: x0 in [0,W-2], y0 in [0,H-2] -> gather needs no clamping
        float x0f = floorf(u), y0f = floorf(v);
        x0[p] = (int)x0f; y0[p] = (int)y0f;
        wx[p] = u - x0f; wy[p] = v - y0f;
        px[p] = X; py[p] = Y; pz[p] = Z; inview[p] = iv;
    }
    // one 16 B gather per in-view pixel: {c00, c10, c01, c11}
    uint4 Q[4];
#pragma unroll
    for (int p = 0; p < 4; p++) {
        if (inview[p]) {
            Q[p] = *reinterpret_cast<const uint4_a8*>(ndp + (size_t)(y0[p] * W_IMG + x0[p]));
        } else {
            Q[p] = make_uint4(0u, 0u, 0u, 0u);  // decoded junk is discarded via occ
        }
    }
#pragma unroll
    for (int p = 0; p < 4; p++) {
        float d00, d10, d01, d11;
        float n00x, n00y, n00z, n10x, n10y, n10z;
        float n01x, n01y, n01z, n11x, n11y, n11z;
        dec4(Q[p].x, dmin, scale, d00, n00x, n00y, n00z);
        dec4(Q[p].y, dmin, scale, d10, n10x, n10y, n10z);
        dec4(Q[p].z, dmin, scale, d01, n01x, n01y, n01z);
        dec4(Q[p].w, dmin, scale, d11, n11x, n11y, n11z);
        float w1x = 1.f - wx[p], w1y = 1.f - wy[p];
        float cX0 = ((float)x0[p] - cx) * ifx, cX1 = ((float)(x0[p] + 1) - cx) * ifx;
        float cY0 = ((float)y0[p] - cy) * ify, cY1 = ((float)(y0[p] + 1) - cy) * ify;
        float rvx = (cX0 * d00 * w1x + cX1 * d01 * wx[p]) * w1y + (cX0 * d10 * w1x + cX1 * d11 * wx[p]) * wy[p];
        float rvy = (cY0 * d00 * w1x + cY0 * d01 * wx[p]) * w1y + (cY1 * d10 * w1x + cY1 * d11 * wx[p]) * wy[p];
        float rvz = (d00 * w1x + d01 * wx[p]) * w1y + (d10 * w1x + d11 * wx[p]) * wy[p];
        float rnx = (n00x * w1x + n01x * wx[p]) * w1y + (n10x * w1x + n11x * wx[p]) * wy[p];
        float rny = (n00y * w1x + n01y * wx[p]) * w1y + (n10y * w1x + n11y * wx[p]) * wy[p];
        float rnz = (n00z * w1x + n01z * wx[p]) * w1y + (n10z * w1x + n11z * wx[p]) * wy[p];
        bool mask1 = rvz > 0.f;
        float ddx = px[p] - rvx, ddy = py[p] - rvy, ddz = pz[p] - rvz;
        bool occ = (!inview[p]) || (sqrtf(ddx * ddx + ddy * ddy + ddz * ddz) > 0.1f);
        bool bad = occ || !(d0s[p] > 0.f) || (!mask1);
        if (!bad) {
            float res = rnx * ddx + rny * ddy + rnz * ddz;
            float jv[6];
            jv[0] = -(py[p] * rnz - pz[p] * rny);
            jv[1] = -(pz[p] * rnx - px[p] * rnz);
            jv[2] = -(px[p] * rny - py[p] * rnx);
            jv[3] = -rnx; jv[4] = -rny; jv[5] = -rnz;
            int k = 0;
#pragma unroll
            for (int a = 0; a < 6; a++)
#pragma unroll
                for (int b = a; b < 6; b++) { acc[k] += jv[a] * jv[b]; k++; }
#pragma unroll
            for (int a = 0; a < 6; a++) acc[21 + a] += jv[a] * res;
        }
    }

    // block reduction: 2x shfl_xor pre-reduce (4 lanes) -> LDS [27][64] -> [27][8] -> f32 partial
    __shared__ float red[NACC][64];
    __shared__ float part2[NACC][8];
#pragma unroll
    for (int k = 0; k < NACC; k++) {
        float v = acc[k];
        v += __shfl_xor(v, 1);
        v += __shfl_xor(v, 2);
        if ((tid & 3) == 0) red[k][tid >> 2] = v;
    }
    __syncthreads();
    if (tid < NACC * 8) {
        int k = tid >> 3, seg = tid & 7;
        const float4* row = reinterpret_cast<const float4*>(&red[k][seg * 8]);
        float4 a = row[0], b = row[1];
        part2[k][seg] = (a.x + a.y + a.z + a.w) + (b.x + b.y + b.z + b.w);
    }
    __syncthreads();
    if (tid < NACC) {
        float s = 0.f;
#pragma unroll
        for (int m = 0; m < 8; m++) s += part2[tid][m];
        partials[(size_t)tid * RB + blockIdx.x] = s;
    }
}

// 27 blocks: block k reduces RB f32 partials (f64); last block runs the 6x6 GN solve.
__global__ __launch_bounds__(256)
void k_reduce_solve(const float* __restrict__ partials, double* __restrict__ sums,
                    unsigned int* __restrict__ counter, float* __restrict__ pose,
                    float* __restrict__ pose_out) {
    int k = blockIdx.x;
    int tid = threadIdx.x;
    double v = 0.0;
    for (int i = tid; i < RB; i += 256) v += (double)partials[(size_t)k * RB + i];
    for (int off = 32; off > 0; off >>= 1) v += __shfl_down(v, off);
    __shared__ double sw[4];
    __shared__ int amLast;
    int lane = tid & 63, wid = tid >> 6;
    if (lane == 0) sw[wid] = v;
    __syncthreads();
    if (tid == 0) {
        sums[k] = sw[0] + sw[1] + sw[2] + sw[3];
        __threadfence();
        unsigned int old = atomicAdd(counter, 1u);
        amLast = (old == NACC - 1) ? 1 : 0;
    }
    __syncthreads();
    if (!amLast) return;
    __threadfence();

    if (tid == 0) {
        double ssum[NACC];
        for (int q = 0; q < NACC; q++) ssum[q] = sums[q];
        double sM[6][7];
        int kk = 0;
        for (int a = 0; a < 6; a++)
            for (int c = a; c < 6; c++) {
                double s = ssum[kk++];
                sM[a][c] = s; sM[c][a] = s;
            }
        double tr = sM[0][0] + sM[1][1] + sM[2][2] + sM[3][3] + sM[4][4] + sM[5][5];
        for (int a = 0; a < 6; a++) sM[a][a] += tr * 0.001;
        for (int a = 0; a < 6; a++) sM[a][6] = ssum[21 + a];
        for (int c = 0; c < 6; c++) {
            int piv = c;
            double best = fabs(sM[c][c]);
            for (int r = c + 1; r < 6; r++) {
                double vv = fabs(sM[r][c]);
                if (vv > best) { best = vv; piv = r; }
            }
            if (piv != c)
                for (int q = c; q < 7; q++) { double t = sM[c][q]; sM[c][q] = sM[piv][q]; sM[piv][q] = t; }
            double pv = sM[c][c];
            for (int r = 0; r < 6; r++) {
                if (r == c) continue;
                double f = sM[r][c] / pv;
                for (int q = c; q < 7; q++) sM[r][q] -= f * sM[c][q];
            }
        }
        double xi0 = sM[0][6] / sM[0][0], xi1 = sM[1][6] / sM[1][1], xi2 = sM[2][6] / sM[2][2];
        double xi3 = sM[3][6] / sM[3][3], xi4 = sM[4][6] / sM[4][4], xi5 = sM[5][6] / sM[5][5];
        double th = sqrt(xi0 * xi0 + xi1 * xi1 + xi2 * xi2);
        double dR[3][3] = {{1, 0, 0}, {0, 1, 0}, {0, 0, 1}};
        if (th > 1e-10) {
            double sA = sin(th) / th;
            double sB = (1.0 - cos(th)) / (th * th);
            double wh[3][3] = {{0, -xi2, xi1}, {xi2, 0, -xi0}, {-xi1, xi0, 0}};
#pragma unroll
            for (int r = 0; r < 3; r++)
#pragma unroll
                for (int cc = 0; cc < 3; cc++) {
                    double w2 = 0;
#pragma unroll
                    for (int m = 0; m < 3; m++) w2 += wh[r][m] * wh[m][cc];
                    dR[r][cc] = (r == cc ? 1.0 : 0.0) + sA * wh[r][cc] + sB * w2;
                }
        }
        double R[3][3], t[3];
#pragma unroll
        for (int r = 0; r < 3; r++) {
#pragma unroll
            for (int cc = 0; cc < 3; cc++) R[r][cc] = pose[r * 4 + cc];
            t[r] = pose[r * 4 + 3];
        }
        double xt[3] = {xi3, xi4, xi5};
#pragma unroll
        for (int r = 0; r < 3; r++) {
#pragma unroll
            for (int cc = 0; cc < 3; cc++) {
                double s = 0;
#pragma unroll
                for (int m = 0; m < 3; m++) s += dR[r][m] * R[m][cc];
                pose[r * 4 + cc] = (float)s;
            }
            pose[r * 4 + 3] = (float)(dR[r][0] * t[0] + dR[r][1] * t[1] + dR[r][2] * t[2] + xt[r]);
        }
        *counter = 0u;                         // re-arm for next dispatch / replay
        for (int q = 0; q < 16; q++) pose_out[q] = pose[q];
    }
}

extern "C" void kernel_launch(void* const* d_in, const int* in_sizes, int n_in,
                              void* d_out, int out_size, void* d_ws, size_t ws_size,
                              hipStream_t stream) {
    const float* pose_in = (const float*)d_in[0];
    const float* depth0 = (const float*)d_in[1];
    const float* depth1 = (const float*)d_in[2];
    const float* K = (const float*)d_in[3];
    float* out = (float*)d_out;
    char* ws = (char*)d_ws;
    float* ws_pose = (float*)(ws + OFF_POSE);
    unsigned int* minmax = (unsigned int*)(ws + OFF_MINMAX);
    unsigned int* counter = (unsigned int*)(ws + OFF_COUNT);
    double* sums = (double*)(ws + OFF_SUMS);
    float* partials = (float*)(ws + OFF_PARTIALS);
    unsigned int* nd4 = (unsigned int*)(ws + OFF_ND4);
    uint2* ndp = (uint2*)(ws + OFF_NDP);

    k_init<<<1, 64, 0, stream>>>(pose_in, ws_pose, minmax, counter);
    k_minmax<<<1024, 256, 0, stream>>>((const float4*)depth1, minmax);
    k_nm<<<RB, 256, 0, stream>>>(depth1, K, minmax, nd4);
    k_pair<<<RB, 256, 0, stream>>>(nd4, ndp);
    for (int it = 0; it < 3; ++it) {
        k_resid<<<RB, 256, 0, stream>>>(depth0, K, ndp, minmax, ws_pose, partials);
        k_reduce_solve<<<NACC, 256, 0, stream>>>(partials, sums, counter, ws_pose, out);
    }
}